// Round 3
// baseline (992.808 us; speedup 1.0000x reference)
//
#include <hip/hip_runtime.h>
#include <hip/hip_bf16.h>

#define NNODES 331776            // 81 * 4096
#define NBLK   1296              // NNODES / 256 (exact)
#define NGRAPH 4096

// ---------------- CSR build ----------------

// 8 edges/thread: independent atomics pipeline (latency /8).
__global__ __launch_bounds__(256) void k_count(const int* __restrict__ dst,
                                               int* __restrict__ cnt, int E) {
    int base = blockIdx.x * (256 * 8) + threadIdx.x;
    int dd[8]; bool ok[8];
#pragma unroll
    for (int i = 0; i < 8; i++) {
        int e = base + i * 256;
        ok[i] = e < E;
        dd[i] = ok[i] ? dst[e] : 0;
    }
#pragma unroll
    for (int i = 0; i < 8; i++)
        if (ok[i]) atomicAdd(&cnt[dd[i]], 1);
}

__global__ void k_scan1(const int* __restrict__ cnt, int* __restrict__ offs,
                        int* __restrict__ bsums) {
    __shared__ int tmp[256];
    int t = threadIdx.x;
    int g = blockIdx.x * 256 + t;
    int v = cnt[g];
    tmp[t] = v; __syncthreads();
    for (int o = 1; o < 256; o <<= 1) {
        int a = (t >= o) ? tmp[t - o] : 0;
        __syncthreads();
        tmp[t] += a;
        __syncthreads();
    }
    offs[g] = tmp[t] - v;                 // exclusive within block
    if (t == 255) bsums[blockIdx.x] = tmp[255];
}

__global__ void k_scan2(int* __restrict__ bsums, int nb) {
    __shared__ int tmp[256];
    __shared__ int carry;
    int t = threadIdx.x;
    if (t == 0) carry = 0;
    __syncthreads();
    for (int base = 0; base < nb; base += 256) {
        int v = (base + t < nb) ? bsums[base + t] : 0;
        tmp[t] = v; __syncthreads();
        for (int o = 1; o < 256; o <<= 1) {
            int a = (t >= o) ? tmp[t - o] : 0;
            __syncthreads();
            tmp[t] += a;
            __syncthreads();
        }
        int excl = tmp[t] - v;
        int tot  = tmp[255];
        if (base + t < nb) bsums[base + t] = excl + carry;
        __syncthreads();
        if (t == 0) carry += tot;
        __syncthreads();
    }
}

__global__ void k_scan3(int* __restrict__ offs, const int* __restrict__ bsums,
                        int* __restrict__ cursor) {
    int g = blockIdx.x * 256 + threadIdx.x;
    int v = offs[g] + bsums[blockIdx.x];
    offs[g] = v;
    cursor[g] = v;
}

// CSR payload: (src, esig) with esig = sign(w)*exp(|w|); exp computed ONCE here.
// 8 edges/thread, phase-split so 8 atomic round-trips are in flight at once.
__global__ __launch_bounds__(256) void k_scatter(
    const int* __restrict__ src, const int* __restrict__ dst,
    const float* __restrict__ w, int* __restrict__ cursor,
    int2* __restrict__ csr, int E) {
    int base = blockIdx.x * (256 * 8) + threadIdx.x;
    int dd[8], sx[8]; float es[8]; bool ok[8]; int p[8];
#pragma unroll
    for (int i = 0; i < 8; i++) {
        int e = base + i * 256;
        ok[i] = e < E;
        if (ok[i]) {
            dd[i] = dst[e];
            sx[i] = src[e];
            float wv = w[e];
            float t = 0.f;
            if (wv > 0.f)      t = __expf(wv);
            else if (wv < 0.f) t = -__expf(-wv);
            es[i] = t;
        }
    }
#pragma unroll
    for (int i = 0; i < 8; i++)
        if (ok[i]) p[i] = atomicAdd(&cursor[dd[i]], 1);
#pragma unroll
    for (int i = 0; i < 8; i++)
        if (ok[i]) {
            int2 sw;
            sw.x = sx[i];
            sw.y = __float_as_int(es[i]);
            csr[p[i]] = sw;
        }
}

// ---------------- Layer 1 (h0 = deg, 1 feature -> 32) ----------------
// Half-wave (32 lanes) per node: edge-parallel lanes, shfl_xor reduction,
// coalesced h1 write (lane f writes feature f).

__global__ __launch_bounds__(256) void k_layer1(
    const int* __restrict__ cnt, const int* __restrict__ offs,
    const int2* __restrict__ csr,
    float* __restrict__ spos, float* __restrict__ sneg,
    float* __restrict__ h1,
    const float* __restrict__ W1, const float* __restrict__ b1,
    const float* __restrict__ bias1,
    const float* __restrict__ c1s, const float* __restrict__ c1p,
    const float* __restrict__ c1n) {
    int t = threadIdx.x;
    int g = t >> 5, f = t & 31;
    int d = blockIdx.x * 8 + g;
    int beg = offs[d];
    int len = cnt[d];
    float sp = 0.f, sn = 0.f, up = 0.f, un = 0.f;
    for (int j = 0; j < len; j += 32) {
        int rem = len - j;
        if (f < rem) {
            int2 sw = csr[beg + j + f];            // coalesced 8B/lane
            float es = __int_as_float(sw.y);
            float degs = (float)cnt[sw.x];          // parallel gather, L2-hot
            float ep = fmaxf(es, 0.f), en = fmaxf(-es, 0.f);
            sp += ep; sn += en; up += degs * ep; un += degs * en;
        }
    }
    for (int m = 16; m; m >>= 1) {
        sp += __shfl_xor(sp, m, 32);
        sn += __shfl_xor(sn, m, 32);
        up += __shfl_xor(up, m, 32);
        un += __shfl_xor(un, m, 32);
    }
    if (f == 0) { spos[d] = sp; sneg[d] = sn; }
    float hp = up / fmaxf(sp, 1e-20f);
    float hn = un / fmaxf(sn, 1e-20f);
    float x0 = c1s[0] * (float)len;   // deg[d] == len
    float x1 = c1p[0] * hp;
    float x2 = c1n[0] * hn;
    float v = W1[f * 3] * x0 + W1[f * 3 + 1] * x1 + W1[f * 3 + 2] * x2
            + b1[f] + bias1[f];
    h1[d * 32 + f] = fmaxf(v, 0.f);                 // coalesced 128B/node
}

// ---------------- Layer 2 + fused conv1 (64 -> 16 per node) ----------------
// 8 nodes per 256-thread block; 32 lanes per node hold the 32 features.
// Edge chunk (32) loaded coalesced once, then shuffle-broadcast inner loop
// with 4-wide manual unroll so h1 gathers pipeline.

__global__ __launch_bounds__(256) void k_layer2(
    const int* __restrict__ cnt, const int* __restrict__ offs,
    const int2* __restrict__ csr,
    const float* __restrict__ spos, const float* __restrict__ sneg,
    const float* __restrict__ h1,
    const float* __restrict__ W2, const float* __restrict__ b2,
    const float* __restrict__ bias2,
    const float* __restrict__ c2s, const float* __restrict__ c2p,
    const float* __restrict__ c2n,
    const float* __restrict__ k1, const float* __restrict__ bk1,
    float* __restrict__ y1) {
    __shared__ float W2s[32][97];   // +1 pad: avoids 32-way bank conflict on o-stride
    __shared__ float k1s[16][65];
    __shared__ float comb[8][97];
    __shared__ float h1s[8][33];
    __shared__ float h2s[8][33];
    int t = threadIdx.x;
    for (int i = t; i < 32 * 96; i += 256) W2s[i / 96][i % 96] = W2[i];
    for (int i = t; i < 16 * 64; i += 256) k1s[i / 64][i % 64] = k1[i];

    int g = t >> 5, f = t & 31;
    int d = blockIdx.x * 8 + g;     // NNODES % 8 == 0
    int beg = offs[d];
    int len = cnt[d];
    float ap = 0.f, an = 0.f;
    for (int j = 0; j < len; j += 32) {
        int rem = len - j;
        int sx = 0;
        float es = 0.f;
        if (f < rem) {
            int2 sw = csr[beg + j + f];            // coalesced 8B/lane
            sx = sw.x;
            es = __int_as_float(sw.y);
        }
        int n = rem < 32 ? rem : 32;
        int q = 0;
        for (; q + 4 <= n; q += 4) {
            int   s0 = __shfl(sx, q,     32);
            int   s1 = __shfl(sx, q + 1, 32);
            int   s2 = __shfl(sx, q + 2, 32);
            int   s3 = __shfl(sx, q + 3, 32);
            float e0 = __shfl(es, q,     32);
            float e1 = __shfl(es, q + 1, 32);
            float e2 = __shfl(es, q + 2, 32);
            float e3 = __shfl(es, q + 3, 32);
            float h0 = h1[s0 * 32 + f];             // 4 independent gathers in flight
            float hv1 = h1[s1 * 32 + f];
            float hv2 = h1[s2 * 32 + f];
            float hv3 = h1[s3 * 32 + f];
            ap += fmaxf(e0, 0.f) * h0;  an += fmaxf(-e0, 0.f) * h0;
            ap += fmaxf(e1, 0.f) * hv1; an += fmaxf(-e1, 0.f) * hv1;
            ap += fmaxf(e2, 0.f) * hv2; an += fmaxf(-e2, 0.f) * hv2;
            ap += fmaxf(e3, 0.f) * hv3; an += fmaxf(-e3, 0.f) * hv3;
        }
        for (; q < n; q++) {
            int   s0 = __shfl(sx, q, 32);
            float e0 = __shfl(es, q, 32);
            float h0 = h1[s0 * 32 + f];
            ap += fmaxf(e0, 0.f) * h0;
            an += fmaxf(-e0, 0.f) * h0;
        }
    }
    ap /= fmaxf(spos[d], 1e-20f);
    an /= fmaxf(sneg[d], 1e-20f);
    float h1v = h1[d * 32 + f];
    comb[g][f]      = c2s[0] * h1v;
    comb[g][f + 32] = c2p[0] * ap;
    comb[g][f + 64] = c2n[0] * an;
    h1s[g][f] = h1v;
    __syncthreads();

    // h2[o] for o = f
    float acc = b2[f] + bias2[f];
    for (int k = 0; k < 96; k++) acc += comb[g][k] * W2s[f][k];
    h2s[g][f] = fmaxf(acc, 0.f);
    __syncthreads();

    // fused conv1: y1[node, o16] = bk1 + k1[o16, :] . [h1 | h2]
    if (t < 128) {
        int gg = t >> 4, o = t & 15;
        float a = bk1[o];
        for (int i = 0; i < 32; i++) a += k1s[o][i]      * h1s[gg][i];
        for (int i = 0; i < 32; i++) a += k1s[o][32 + i] * h2s[gg][i];
        int node = blockIdx.x * 8 + gg;
        y1[node * 16 + o] = a;
    }
}

// ---------------- Wfc transpose (for coalesced FC reads) ----------------

__global__ void k_transpose(const float* __restrict__ Wfc, float* __restrict__ WfcT) {
    int i = blockIdx.x * 256 + threadIdx.x;
    if (i < 128 * 416) {
        int u = i / 416, c = i - u * 416;
        WfcT[c * 128 + u] = Wfc[i];
    }
}

// ---------------- Head: maxpool -> conv2 -> FC -> classifier -> log_softmax ----

__global__ __launch_bounds__(128) void k_head(
    const float* __restrict__ y1, const float* __restrict__ k2,
    const float* __restrict__ bk2, const float* __restrict__ WfcT,
    const float* __restrict__ bfc, const float* __restrict__ Wc,
    const float* __restrict__ bc, float* __restrict__ out) {
    __shared__ float yl[1296];       // 81 positions x 16 ch, [p][ch]
    __shared__ float zl[16][41];     // after maxpool, [ch][pos<40], pad
    __shared__ float xr[416];        // conv2 out, index oc*13+t
    __shared__ float k2s[1536];
    __shared__ float fl[128];
    __shared__ float ll[10];
    int t = threadIdx.x;
    int b = blockIdx.x;
    const float* yb = y1 + (size_t)b * 1296;
    for (int i = t; i < 1296; i += 128) yl[i] = yb[i];
    for (int i = t; i < 1536; i += 128) k2s[i] = k2[i];
    __syncthreads();
    // maxpool over position pairs (drop pos 80)
    for (int i = t; i < 640; i += 128) {
        int ic = i & 15, p = i >> 4;
        zl[ic][p] = fmaxf(yl[(2 * p) * 16 + ic], yl[(2 * p + 1) * 16 + ic]);
    }
    __syncthreads();
    // conv2: 32 out-ch x 13 positions, stride 3, k=3
    for (int i = t; i < 416; i += 128) {
        int oc = i / 13, tt = i - oc * 13;
        float acc = bk2[oc];
        for (int ic = 0; ic < 16; ic++) {
            const float* kk = &k2s[(oc * 16 + ic) * 3];
            acc += zl[ic][3 * tt]     * kk[0]
                 + zl[ic][3 * tt + 1] * kk[1]
                 + zl[ic][3 * tt + 2] * kk[2];
        }
        xr[i] = acc;
    }
    __syncthreads();
    // FC 416 -> 128, one thread per output, coalesced WfcT reads
    {
        float acc = bfc[t];
        for (int i = 0; i < 416; i++) acc += xr[i] * WfcT[i * 128 + t];
        fl[t] = fmaxf(acc, 0.f);
    }
    __syncthreads();
    if (t < 10) {
        float acc = bc[t];
        for (int u = 0; u < 128; u++) acc += fl[u] * Wc[t * 128 + u];
        ll[t] = acc;
    }
    __syncthreads();
    if (t < 10) {
        float m = -1e30f;
        for (int c = 0; c < 10; c++) m = fmaxf(m, ll[c]);
        float s = 0.f;
        for (int c = 0; c < 10; c++) s += __expf(ll[c] - m);
        out[b * 10 + t] = ll[t] - m - __logf(s);
    }
}

// ---------------- launch ----------------

extern "C" void kernel_launch(void* const* d_in, const int* in_sizes, int n_in,
                              void* d_out, int out_size, void* d_ws, size_t ws_size,
                              hipStream_t stream) {
    const int*   src   = (const int*)d_in[0];
    const int*   dst   = (const int*)d_in[1];
    const float* w     = (const float*)d_in[2];
    const float* W1    = (const float*)d_in[4];
    const float* b1    = (const float*)d_in[5];
    const float* bias1 = (const float*)d_in[6];
    const float* c1s   = (const float*)d_in[7];
    const float* c1p   = (const float*)d_in[8];
    const float* c1n   = (const float*)d_in[9];
    const float* W2    = (const float*)d_in[10];
    const float* b2    = (const float*)d_in[11];
    const float* bias2 = (const float*)d_in[12];
    const float* c2s   = (const float*)d_in[13];
    const float* c2p   = (const float*)d_in[14];
    const float* c2n   = (const float*)d_in[15];
    const float* k1    = (const float*)d_in[16];
    const float* bk1   = (const float*)d_in[17];
    const float* k2    = (const float*)d_in[18];
    const float* bk2   = (const float*)d_in[19];
    const float* Wfc   = (const float*)d_in[20];
    const float* bfc   = (const float*)d_in[21];
    const float* Wc    = (const float*)d_in[22];
    const float* bc    = (const float*)d_in[23];
    const int E = in_sizes[0];

    // workspace carve (256B aligned)
    size_t off = 0;
    auto carve = [&](size_t bytes) -> char* {
        char* p = (char*)d_ws + off;
        off = (off + bytes + 255) & ~(size_t)255;
        return p;
    };
    int*   cnt    = (int*)  carve((size_t)NNODES * 4);
    int*   offs   = (int*)  carve((size_t)NNODES * 4);
    int*   cursor = (int*)  carve((size_t)NNODES * 4);
    int*   bsums  = (int*)  carve((size_t)NBLK * 4);
    int2*  csr    = (int2*) carve((size_t)E * 8);
    float* spos   = (float*)carve((size_t)NNODES * 4);
    float* sneg   = (float*)carve((size_t)NNODES * 4);
    float* h1     = (float*)carve((size_t)NNODES * 32 * 4);
    float* y1     = (float*)carve((size_t)NNODES * 16 * 4);
    float* WfcT   = (float*)carve((size_t)128 * 416 * 4);
    (void)ws_size;

    hipMemsetAsync(cnt, 0, (size_t)NNODES * 4, stream);

    int eb8 = (E + 2047) / 2048;
    k_count  <<<eb8, 256, 0, stream>>>(dst, cnt, E);
    k_scan1  <<<NBLK, 256, 0, stream>>>(cnt, offs, bsums);
    k_scan2  <<<1, 256, 0, stream>>>(bsums, NBLK);
    k_scan3  <<<NBLK, 256, 0, stream>>>(offs, bsums, cursor);
    k_scatter<<<eb8, 256, 0, stream>>>(src, dst, w, cursor, csr, E);
    k_layer1 <<<NNODES / 8, 256, 0, stream>>>(cnt, offs, csr, spos, sneg, h1,
                                              W1, b1, bias1, c1s, c1p, c1n);
    k_transpose<<<(128 * 416 + 255) / 256, 256, 0, stream>>>(Wfc, WfcT);
    k_layer2 <<<NNODES / 8, 256, 0, stream>>>(cnt, offs, csr, spos, sneg, h1,
                                              W2, b2, bias2, c2s, c2p, c2n,
                                              k1, bk1, y1);
    k_head   <<<NGRAPH, 128, 0, stream>>>(y1, k2, bk2, WfcT, bfc, Wc, bc,
                                          (float*)d_out);
}

// Round 4
// 680.712 us; speedup vs baseline: 1.4585x; 1.4585x over previous
//
#include <hip/hip_runtime.h>
#include <hip/hip_bf16.h>

#define NNODES 331776            // 81 * 4096
#define NGRAPH 4096
#define NBUCK  2048              // buckets
#define BNODES 162               // nodes per bucket (2048*162 == 331776)
#define TE     16384             // edges per tile
#define CAP    2560              // max edges/bucket (lambda=1953, 13.7 sigma)

// ---------------- deterministic bucket sort (no global atomics) ----------------

__global__ __launch_bounds__(256) void k_hist(const int* __restrict__ dst,
                                              int* __restrict__ H, int E) {
    __shared__ int h[NBUCK];
    int t = threadIdx.x, b = blockIdx.x;
    for (int i = t; i < NBUCK; i += 256) h[i] = 0;
    __syncthreads();
    int lo = b * TE, hi = min(E, lo + TE);
    for (int e = lo + t; e < hi; e += 256)
        atomicAdd(&h[dst[e] / BNODES], 1);
    __syncthreads();
    for (int i = t; i < NBUCK; i += 256) H[b * NBUCK + i] = h[i];
}

// per-bucket exclusive scan across tiles (in place); T[bin] = total
__global__ void k_colscan(int* __restrict__ H, int* __restrict__ T, int NT) {
    int bin = blockIdx.x * 256 + threadIdx.x;
    int s = 0;
    for (int t = 0; t < NT; t++) {
        int v = H[t * NBUCK + bin];
        H[t * NBUCK + bin] = s;
        s += v;
    }
    T[bin] = s;
}

// exclusive scan over the 2048 bucket totals -> Bstart[0..NBUCK]
__global__ __launch_bounds__(256) void k_binscan(const int* __restrict__ T,
                                                 int* __restrict__ Bstart) {
    __shared__ int tmp[256];
    int t = threadIdx.x;
    int base = t * 8;
    int loc[8]; int s = 0;
#pragma unroll
    for (int i = 0; i < 8; i++) { loc[i] = s; s += T[base + i]; }
    tmp[t] = s; __syncthreads();
    for (int o = 1; o < 256; o <<= 1) {
        int a = (t >= o) ? tmp[t - o] : 0;
        __syncthreads();
        tmp[t] += a;
        __syncthreads();
    }
    int excl = tmp[t] - s;
#pragma unroll
    for (int i = 0; i < 8; i++) Bstart[base + i] = excl + loc[i];
    if (t == 255) Bstart[NBUCK] = excl + s;
}

// place edges into bucket-major order; payload packs (src | dst_local<<19, esig)
// esig = sign(w)*exp(|w|) computed once here.
__global__ __launch_bounds__(256) void k_place(
    const int* __restrict__ src, const int* __restrict__ dst,
    const float* __restrict__ w,
    const int* __restrict__ H, const int* __restrict__ Bstart,
    int2* __restrict__ csrB, int E) {
    __shared__ int cur[NBUCK];
    int t = threadIdx.x, b = blockIdx.x;
    for (int i = t; i < NBUCK; i += 256)
        cur[i] = Bstart[i] + H[b * NBUCK + i];
    __syncthreads();
    int lo = b * TE, hi = min(E, lo + TE);
    for (int e = lo + t; e < hi; e += 256) {
        int d  = dst[e];
        int sx = src[e];
        float wv = w[e];
        float es = 0.f;
        if (wv > 0.f)      es = __expf(wv);
        else if (wv < 0.f) es = -__expf(-wv);
        int bin = d / BNODES;
        int dl  = d - bin * BNODES;
        int p = atomicAdd(&cur[bin], 1);        // LDS atomic; same-bin runs -> consecutive p
        int2 pk;
        pk.x = sx | (dl << 19);
        pk.y = __float_as_int(es);
        csrB[p] = pk;
    }
}

// per-bucket counting sort (in place), emits cnt[] and offs[] for free.
__global__ __launch_bounds__(256) void k_sortbucket(
    int2* __restrict__ csrB, const int* __restrict__ Bstart,
    int* __restrict__ cnt, int* __restrict__ offs) {
    __shared__ int2 pb[CAP];
    __shared__ int lcnt[BNODES];
    __shared__ int lpos[BNODES];
    int t = threadIdx.x, b = blockIdx.x;
    int lo = Bstart[b];
    int S  = Bstart[b + 1] - lo;
    if (S > CAP) S = CAP;                        // memory-safety guard (never expected)
    for (int i = t; i < BNODES; i += 256) lcnt[i] = 0;
    __syncthreads();
    for (int i = t; i < S; i += 256) {
        int2 pk = csrB[lo + i];                  // coalesced
        pb[i] = pk;
        atomicAdd(&lcnt[pk.x >> 19], 1);
    }
    __syncthreads();
    if (t == 0) {
        int s = 0;
        for (int i = 0; i < BNODES; i++) { lpos[i] = s; s += lcnt[i]; }
    }
    __syncthreads();
    int node0 = b * BNODES;
    for (int i = t; i < BNODES; i += 256) {
        cnt[node0 + i]  = lcnt[i];
        offs[node0 + i] = lo + lpos[i];
    }
    __syncthreads();
    for (int i = t; i < S; i += 256) {
        int2 pk = pb[i];
        int dl = pk.x >> 19;
        int p = atomicAdd(&lpos[dl], 1);
        int2 outv;
        outv.x = pk.x & 0x7FFFF;                 // unpacked src
        outv.y = pk.y;                           // esig
        csrB[lo + p] = outv;                     // bucket-local, L2-hot
    }
}

// ---------------- Layer 1 (h0 = deg, 1 feature -> 32) ----------------
// Half-wave (32 lanes) per node: edge-parallel lanes, shfl_xor reduction,
// coalesced h1 write (lane f writes feature f).

__global__ __launch_bounds__(256) void k_layer1(
    const int* __restrict__ cnt, const int* __restrict__ offs,
    const int2* __restrict__ csr,
    float* __restrict__ spos, float* __restrict__ sneg,
    float* __restrict__ h1,
    const float* __restrict__ W1, const float* __restrict__ b1,
    const float* __restrict__ bias1,
    const float* __restrict__ c1s, const float* __restrict__ c1p,
    const float* __restrict__ c1n) {
    int t = threadIdx.x;
    int g = t >> 5, f = t & 31;
    int d = blockIdx.x * 8 + g;
    int beg = offs[d];
    int len = cnt[d];
    float sp = 0.f, sn = 0.f, up = 0.f, un = 0.f;
    for (int j = 0; j < len; j += 32) {
        int rem = len - j;
        if (f < rem) {
            int2 sw = csr[beg + j + f];            // coalesced 8B/lane
            float es = __int_as_float(sw.y);
            float degs = (float)cnt[sw.x];          // parallel gather, L2-hot
            float ep = fmaxf(es, 0.f), en = fmaxf(-es, 0.f);
            sp += ep; sn += en; up += degs * ep; un += degs * en;
        }
    }
    for (int m = 16; m; m >>= 1) {
        sp += __shfl_xor(sp, m, 32);
        sn += __shfl_xor(sn, m, 32);
        up += __shfl_xor(up, m, 32);
        un += __shfl_xor(un, m, 32);
    }
    if (f == 0) { spos[d] = sp; sneg[d] = sn; }
    float hp = up / fmaxf(sp, 1e-20f);
    float hn = un / fmaxf(sn, 1e-20f);
    float x0 = c1s[0] * (float)len;   // deg[d] == len
    float x1 = c1p[0] * hp;
    float x2 = c1n[0] * hn;
    float v = W1[f * 3] * x0 + W1[f * 3 + 1] * x1 + W1[f * 3 + 2] * x2
            + b1[f] + bias1[f];
    h1[d * 32 + f] = fmaxf(v, 0.f);                 // coalesced 128B/node
}

// ---------------- Layer 2 + fused conv1 (64 -> 16 per node) ----------------

__global__ __launch_bounds__(256) void k_layer2(
    const int* __restrict__ cnt, const int* __restrict__ offs,
    const int2* __restrict__ csr,
    const float* __restrict__ spos, const float* __restrict__ sneg,
    const float* __restrict__ h1,
    const float* __restrict__ W2, const float* __restrict__ b2,
    const float* __restrict__ bias2,
    const float* __restrict__ c2s, const float* __restrict__ c2p,
    const float* __restrict__ c2n,
    const float* __restrict__ k1, const float* __restrict__ bk1,
    float* __restrict__ y1) {
    __shared__ float W2s[32][97];   // +1 pad: avoids 32-way bank conflict on o-stride
    __shared__ float k1s[16][65];
    __shared__ float comb[8][97];
    __shared__ float h1s[8][33];
    __shared__ float h2s[8][33];
    int t = threadIdx.x;
    for (int i = t; i < 32 * 96; i += 256) W2s[i / 96][i % 96] = W2[i];
    for (int i = t; i < 16 * 64; i += 256) k1s[i / 64][i % 64] = k1[i];

    int g = t >> 5, f = t & 31;
    int d = blockIdx.x * 8 + g;     // NNODES % 8 == 0
    int beg = offs[d];
    int len = cnt[d];
    float ap = 0.f, an = 0.f;
    for (int j = 0; j < len; j += 32) {
        int rem = len - j;
        int sx = 0;
        float es = 0.f;
        if (f < rem) {
            int2 sw = csr[beg + j + f];            // coalesced 8B/lane
            sx = sw.x;
            es = __int_as_float(sw.y);
        }
        int n = rem < 32 ? rem : 32;
        int q = 0;
        for (; q + 4 <= n; q += 4) {
            int   s0 = __shfl(sx, q,     32);
            int   s1 = __shfl(sx, q + 1, 32);
            int   s2 = __shfl(sx, q + 2, 32);
            int   s3 = __shfl(sx, q + 3, 32);
            float e0 = __shfl(es, q,     32);
            float e1 = __shfl(es, q + 1, 32);
            float e2 = __shfl(es, q + 2, 32);
            float e3 = __shfl(es, q + 3, 32);
            float h0 = h1[s0 * 32 + f];             // 4 independent gathers in flight
            float hv1 = h1[s1 * 32 + f];
            float hv2 = h1[s2 * 32 + f];
            float hv3 = h1[s3 * 32 + f];
            ap += fmaxf(e0, 0.f) * h0;  an += fmaxf(-e0, 0.f) * h0;
            ap += fmaxf(e1, 0.f) * hv1; an += fmaxf(-e1, 0.f) * hv1;
            ap += fmaxf(e2, 0.f) * hv2; an += fmaxf(-e2, 0.f) * hv2;
            ap += fmaxf(e3, 0.f) * hv3; an += fmaxf(-e3, 0.f) * hv3;
        }
        for (; q < n; q++) {
            int   s0 = __shfl(sx, q, 32);
            float e0 = __shfl(es, q, 32);
            float h0 = h1[s0 * 32 + f];
            ap += fmaxf(e0, 0.f) * h0;
            an += fmaxf(-e0, 0.f) * h0;
        }
    }
    ap /= fmaxf(spos[d], 1e-20f);
    an /= fmaxf(sneg[d], 1e-20f);
    float h1v = h1[d * 32 + f];
    comb[g][f]      = c2s[0] * h1v;
    comb[g][f + 32] = c2p[0] * ap;
    comb[g][f + 64] = c2n[0] * an;
    h1s[g][f] = h1v;
    __syncthreads();

    // h2[o] for o = f
    float acc = b2[f] + bias2[f];
    for (int k = 0; k < 96; k++) acc += comb[g][k] * W2s[f][k];
    h2s[g][f] = fmaxf(acc, 0.f);
    __syncthreads();

    // fused conv1: y1[node, o16] = bk1 + k1[o16, :] . [h1 | h2]
    if (t < 128) {
        int gg = t >> 4, o = t & 15;
        float a = bk1[o];
        for (int i = 0; i < 32; i++) a += k1s[o][i]      * h1s[gg][i];
        for (int i = 0; i < 32; i++) a += k1s[o][32 + i] * h2s[gg][i];
        int node = blockIdx.x * 8 + gg;
        y1[node * 16 + o] = a;
    }
}

// ---------------- Wfc transpose (for coalesced FC reads) ----------------

__global__ void k_transpose(const float* __restrict__ Wfc, float* __restrict__ WfcT) {
    int i = blockIdx.x * 256 + threadIdx.x;
    if (i < 128 * 416) {
        int u = i / 416, c = i - u * 416;
        WfcT[c * 128 + u] = Wfc[i];
    }
}

// ---------------- Head: maxpool -> conv2 -> FC -> classifier -> log_softmax ----

__global__ __launch_bounds__(128) void k_head(
    const float* __restrict__ y1, const float* __restrict__ k2,
    const float* __restrict__ bk2, const float* __restrict__ WfcT,
    const float* __restrict__ bfc, const float* __restrict__ Wc,
    const float* __restrict__ bc, float* __restrict__ out) {
    __shared__ float yl[1296];       // 81 positions x 16 ch, [p][ch]
    __shared__ float zl[16][41];     // after maxpool, [ch][pos<40], pad
    __shared__ float xr[416];        // conv2 out, index oc*13+t
    __shared__ float k2s[1536];
    __shared__ float fl[128];
    __shared__ float ll[10];
    int t = threadIdx.x;
    int b = blockIdx.x;
    const float* yb = y1 + (size_t)b * 1296;
    for (int i = t; i < 1296; i += 128) yl[i] = yb[i];
    for (int i = t; i < 1536; i += 128) k2s[i] = k2[i];
    __syncthreads();
    // maxpool over position pairs (drop pos 80)
    for (int i = t; i < 640; i += 128) {
        int ic = i & 15, p = i >> 4;
        zl[ic][p] = fmaxf(yl[(2 * p) * 16 + ic], yl[(2 * p + 1) * 16 + ic]);
    }
    __syncthreads();
    // conv2: 32 out-ch x 13 positions, stride 3, k=3
    for (int i = t; i < 416; i += 128) {
        int oc = i / 13, tt = i - oc * 13;
        float acc = bk2[oc];
        for (int ic = 0; ic < 16; ic++) {
            const float* kk = &k2s[(oc * 16 + ic) * 3];
            acc += zl[ic][3 * tt]     * kk[0]
                 + zl[ic][3 * tt + 1] * kk[1]
                 + zl[ic][3 * tt + 2] * kk[2];
        }
        xr[i] = acc;
    }
    __syncthreads();
    // FC 416 -> 128, one thread per output, coalesced WfcT reads
    {
        float acc = bfc[t];
        for (int i = 0; i < 416; i++) acc += xr[i] * WfcT[i * 128 + t];
        fl[t] = fmaxf(acc, 0.f);
    }
    __syncthreads();
    if (t < 10) {
        float acc = bc[t];
        for (int u = 0; u < 128; u++) acc += fl[u] * Wc[t * 128 + u];
        ll[t] = acc;
    }
    __syncthreads();
    if (t < 10) {
        float m = -1e30f;
        for (int c = 0; c < 10; c++) m = fmaxf(m, ll[c]);
        float s = 0.f;
        for (int c = 0; c < 10; c++) s += __expf(ll[c] - m);
        out[b * 10 + t] = ll[t] - m - __logf(s);
    }
}

// ---------------- launch ----------------

extern "C" void kernel_launch(void* const* d_in, const int* in_sizes, int n_in,
                              void* d_out, int out_size, void* d_ws, size_t ws_size,
                              hipStream_t stream) {
    const int*   src   = (const int*)d_in[0];
    const int*   dst   = (const int*)d_in[1];
    const float* w     = (const float*)d_in[2];
    const float* W1    = (const float*)d_in[4];
    const float* b1    = (const float*)d_in[5];
    const float* bias1 = (const float*)d_in[6];
    const float* c1s   = (const float*)d_in[7];
    const float* c1p   = (const float*)d_in[8];
    const float* c1n   = (const float*)d_in[9];
    const float* W2    = (const float*)d_in[10];
    const float* b2    = (const float*)d_in[11];
    const float* bias2 = (const float*)d_in[12];
    const float* c2s   = (const float*)d_in[13];
    const float* c2p   = (const float*)d_in[14];
    const float* c2n   = (const float*)d_in[15];
    const float* k1    = (const float*)d_in[16];
    const float* bk1   = (const float*)d_in[17];
    const float* k2    = (const float*)d_in[18];
    const float* bk2   = (const float*)d_in[19];
    const float* Wfc   = (const float*)d_in[20];
    const float* bfc   = (const float*)d_in[21];
    const float* Wc    = (const float*)d_in[22];
    const float* bc    = (const float*)d_in[23];
    const int E = in_sizes[0];
    const int NT = (E + TE - 1) / TE;

    // workspace carve (256B aligned)
    size_t off = 0;
    auto carve = [&](size_t bytes) -> char* {
        char* p = (char*)d_ws + off;
        off = (off + bytes + 255) & ~(size_t)255;
        return p;
    };
    int*   cnt    = (int*)  carve((size_t)NNODES * 4);
    int*   offs   = (int*)  carve((size_t)NNODES * 4);
    int2*  csrB   = (int2*) carve((size_t)E * 8);
    int*   H      = (int*)  carve((size_t)NT * NBUCK * 4);
    int*   T      = (int*)  carve((size_t)NBUCK * 4);
    int*   Bstart = (int*)  carve((size_t)(NBUCK + 1) * 4);
    float* spos   = (float*)carve((size_t)NNODES * 4);
    float* sneg   = (float*)carve((size_t)NNODES * 4);
    float* h1     = (float*)carve((size_t)NNODES * 32 * 4);
    float* y1     = (float*)carve((size_t)NNODES * 16 * 4);
    float* WfcT   = (float*)carve((size_t)128 * 416 * 4);
    (void)ws_size;

    k_hist     <<<NT, 256, 0, stream>>>(dst, H, E);
    k_colscan  <<<NBUCK / 256, 256, 0, stream>>>(H, T, NT);
    k_binscan  <<<1, 256, 0, stream>>>(T, Bstart);
    k_place    <<<NT, 256, 0, stream>>>(src, dst, w, H, Bstart, csrB, E);
    k_sortbucket<<<NBUCK, 256, 0, stream>>>(csrB, Bstart, cnt, offs);
    k_layer1   <<<NNODES / 8, 256, 0, stream>>>(cnt, offs, csrB, spos, sneg, h1,
                                                W1, b1, bias1, c1s, c1p, c1n);
    k_transpose<<<(128 * 416 + 255) / 256, 256, 0, stream>>>(Wfc, WfcT);
    k_layer2   <<<NNODES / 8, 256, 0, stream>>>(cnt, offs, csrB, spos, sneg, h1,
                                                W2, b2, bias2, c2s, c2p, c2n,
                                                k1, bk1, y1);
    k_head     <<<NGRAPH, 128, 0, stream>>>(y1, k2, bk2, WfcT, bfc, Wc, bc,
                                            (float*)d_out);
}

// Round 5
// 649.135 us; speedup vs baseline: 1.5294x; 1.0486x over previous
//
#include <hip/hip_runtime.h>
#include <hip/hip_bf16.h>

#define NNODES 331776            // 81 * 4096
#define NGRAPH 4096
#define NBUCK  2048              // buckets
#define BNODES 162               // nodes per bucket (2048*162 == 331776)
#define TE     16384             // edges per tile
#define CAP    2560              // max edges/bucket (lambda=1953, 13.7 sigma)

// ---------------- deterministic bucket sort (no global atomics) ----------------

__global__ __launch_bounds__(256) void k_hist(const int* __restrict__ dst,
                                              int* __restrict__ H, int E) {
    __shared__ int h[NBUCK];
    int t = threadIdx.x, b = blockIdx.x;
    for (int i = t; i < NBUCK; i += 256) h[i] = 0;
    __syncthreads();
    int lo = b * TE, hi = min(E, lo + TE);
    for (int e = lo + t; e < hi; e += 256)
        atomicAdd(&h[dst[e] / BNODES], 1);
    __syncthreads();
    for (int i = t; i < NBUCK; i += 256) H[b * NBUCK + i] = h[i];
}

// per-bucket exclusive scan across tiles (in place); T[bin] = total
__global__ void k_colscan(int* __restrict__ H, int* __restrict__ T, int NT) {
    int bin = blockIdx.x * 256 + threadIdx.x;
    int s = 0;
    for (int t = 0; t < NT; t++) {
        int v = H[t * NBUCK + bin];
        H[t * NBUCK + bin] = s;
        s += v;
    }
    T[bin] = s;
}

// exclusive scan over the 2048 bucket totals -> Bstart[0..NBUCK]
__global__ __launch_bounds__(256) void k_binscan(const int* __restrict__ T,
                                                 int* __restrict__ Bstart) {
    __shared__ int tmp[256];
    int t = threadIdx.x;
    int base = t * 8;
    int loc[8]; int s = 0;
#pragma unroll
    for (int i = 0; i < 8; i++) { loc[i] = s; s += T[base + i]; }
    tmp[t] = s; __syncthreads();
    for (int o = 1; o < 256; o <<= 1) {
        int a = (t >= o) ? tmp[t - o] : 0;
        __syncthreads();
        tmp[t] += a;
        __syncthreads();
    }
    int excl = tmp[t] - s;
#pragma unroll
    for (int i = 0; i < 8; i++) Bstart[base + i] = excl + loc[i];
    if (t == 255) Bstart[NBUCK] = excl + s;
}

// place edges into bucket-major order; payload packs (src | dst_local<<19, esig)
// esig = sign(w)*exp(|w|) computed once here.
__global__ __launch_bounds__(256) void k_place(
    const int* __restrict__ src, const int* __restrict__ dst,
    const float* __restrict__ w,
    const int* __restrict__ H, const int* __restrict__ Bstart,
    int2* __restrict__ csrB, int E) {
    __shared__ int cur[NBUCK];
    int t = threadIdx.x, b = blockIdx.x;
    for (int i = t; i < NBUCK; i += 256)
        cur[i] = Bstart[i] + H[b * NBUCK + i];
    __syncthreads();
    int lo = b * TE, hi = min(E, lo + TE);
    for (int e = lo + t; e < hi; e += 256) {
        int d  = dst[e];
        int sx = src[e];
        float wv = w[e];
        float es = 0.f;
        if (wv > 0.f)      es = __expf(wv);
        else if (wv < 0.f) es = -__expf(-wv);
        int bin = d / BNODES;
        int dl  = d - bin * BNODES;
        int p = atomicAdd(&cur[bin], 1);        // LDS atomic; same-bin runs -> consecutive p
        int2 pk;
        pk.x = sx | (dl << 19);
        pk.y = __float_as_int(es);
        csrB[p] = pk;
    }
}

// per-bucket counting sort (in place), emits cnt[] and offs[] for free.
__global__ __launch_bounds__(256) void k_sortbucket(
    int2* __restrict__ csrB, const int* __restrict__ Bstart,
    int* __restrict__ cnt, int* __restrict__ offs) {
    __shared__ int2 pb[CAP];
    __shared__ int lcnt[BNODES];
    __shared__ int lpos[BNODES];
    int t = threadIdx.x, b = blockIdx.x;
    int lo = Bstart[b];
    int S  = Bstart[b + 1] - lo;
    if (S > CAP) S = CAP;                        // memory-safety guard (never expected)
    for (int i = t; i < BNODES; i += 256) lcnt[i] = 0;
    __syncthreads();
    for (int i = t; i < S; i += 256) {
        int2 pk = csrB[lo + i];                  // coalesced
        pb[i] = pk;
        atomicAdd(&lcnt[pk.x >> 19], 1);
    }
    __syncthreads();
    if (t == 0) {
        int s = 0;
        for (int i = 0; i < BNODES; i++) { lpos[i] = s; s += lcnt[i]; }
    }
    __syncthreads();
    int node0 = b * BNODES;
    for (int i = t; i < BNODES; i += 256) {
        cnt[node0 + i]  = lcnt[i];
        offs[node0 + i] = lo + lpos[i];
    }
    __syncthreads();
    for (int i = t; i < S; i += 256) {
        int2 pk = pb[i];
        int dl = pk.x >> 19;
        int p = atomicAdd(&lpos[dl], 1);
        int2 outv;
        outv.x = pk.x & 0x7FFFF;                 // unpacked src
        outv.y = pk.y;                           // esig
        csrB[lo + p] = outv;                     // bucket-local, L2-hot
    }
}

// ---------------- Layer 1 (h0 = deg, 1 feature -> 32) ----------------

__global__ __launch_bounds__(256) void k_layer1(
    const int* __restrict__ cnt, const int* __restrict__ offs,
    const int2* __restrict__ csr,
    float* __restrict__ spos, float* __restrict__ sneg,
    float* __restrict__ h1,
    const float* __restrict__ W1, const float* __restrict__ b1,
    const float* __restrict__ bias1,
    const float* __restrict__ c1s, const float* __restrict__ c1p,
    const float* __restrict__ c1n) {
    int t = threadIdx.x;
    int g = t >> 5, f = t & 31;
    int d = blockIdx.x * 8 + g;
    int beg = offs[d];
    int len = cnt[d];
    float sp = 0.f, sn = 0.f, up = 0.f, un = 0.f;
    for (int j = 0; j < len; j += 32) {
        int rem = len - j;
        if (f < rem) {
            int2 sw = csr[beg + j + f];            // coalesced 8B/lane
            float es = __int_as_float(sw.y);
            float degs = (float)cnt[sw.x];          // parallel gather, L2-hot
            float ep = fmaxf(es, 0.f), en = fmaxf(-es, 0.f);
            sp += ep; sn += en; up += degs * ep; un += degs * en;
        }
    }
    for (int m = 16; m; m >>= 1) {
        sp += __shfl_xor(sp, m, 32);
        sn += __shfl_xor(sn, m, 32);
        up += __shfl_xor(up, m, 32);
        un += __shfl_xor(un, m, 32);
    }
    if (f == 0) { spos[d] = sp; sneg[d] = sn; }
    float hp = up / fmaxf(sp, 1e-20f);
    float hn = un / fmaxf(sn, 1e-20f);
    float x0 = c1s[0] * (float)len;   // deg[d] == len
    float x1 = c1p[0] * hp;
    float x2 = c1n[0] * hn;
    float v = W1[f * 3] * x0 + W1[f * 3 + 1] * x1 + W1[f * 3 + 2] * x2
            + b1[f] + bias1[f];
    h1[d * 32 + f] = fmaxf(v, 0.f);                 // coalesced 128B/node
}

// ---------------- Layer-2 aggregation only (no LDS -> max occupancy) ----------
// Half-wave per node; writes normalized hp/hn planes coalesced.

__global__ __launch_bounds__(256) void k_agg(
    const int* __restrict__ cnt, const int* __restrict__ offs,
    const int2* __restrict__ csr,
    const float* __restrict__ spos, const float* __restrict__ sneg,
    const float* __restrict__ h1,
    float* __restrict__ hp, float* __restrict__ hn) {
    int t = threadIdx.x;
    int g = t >> 5, f = t & 31;
    int d = blockIdx.x * 8 + g;     // NNODES % 8 == 0
    int beg = offs[d];
    int len = cnt[d];
    float ap = 0.f, an = 0.f;
    for (int j = 0; j < len; j += 32) {
        int rem = len - j;
        int sx = 0;
        float es = 0.f;
        if (f < rem) {
            int2 sw = csr[beg + j + f];            // coalesced 8B/lane
            sx = sw.x;
            es = __int_as_float(sw.y);
        }
        int n = rem < 32 ? rem : 32;
        int q = 0;
        for (; q + 4 <= n; q += 4) {
            int   s0 = __shfl(sx, q,     32);
            int   s1 = __shfl(sx, q + 1, 32);
            int   s2 = __shfl(sx, q + 2, 32);
            int   s3 = __shfl(sx, q + 3, 32);
            float e0 = __shfl(es, q,     32);
            float e1 = __shfl(es, q + 1, 32);
            float e2 = __shfl(es, q + 2, 32);
            float e3 = __shfl(es, q + 3, 32);
            float h0  = h1[s0 * 32 + f];            // 4 independent gathers in flight
            float hv1 = h1[s1 * 32 + f];
            float hv2 = h1[s2 * 32 + f];
            float hv3 = h1[s3 * 32 + f];
            ap += fmaxf(e0, 0.f) * h0;  an += fmaxf(-e0, 0.f) * h0;
            ap += fmaxf(e1, 0.f) * hv1; an += fmaxf(-e1, 0.f) * hv1;
            ap += fmaxf(e2, 0.f) * hv2; an += fmaxf(-e2, 0.f) * hv2;
            ap += fmaxf(e3, 0.f) * hv3; an += fmaxf(-e3, 0.f) * hv3;
        }
        for (; q < n; q++) {
            int   s0 = __shfl(sx, q, 32);
            float e0 = __shfl(es, q, 32);
            float h0 = h1[s0 * 32 + f];
            ap += fmaxf(e0, 0.f) * h0;
            an += fmaxf(-e0, 0.f) * h0;
        }
    }
    hp[d * 32 + f] = ap / fmaxf(spos[d], 1e-20f);
    hn[d * 32 + f] = an / fmaxf(sneg[d], 1e-20f);
}

// ---------------- Layer-2 MLP + fused conv1, one THREAD per node -------------
// h1/hp/hn rows in registers; W2/k1 via uniform (scalar) loads -> SGPR/K$.
// y1[16] accumulated in registers; h2 never materialized.

__global__ __launch_bounds__(256) void k_mlp(
    const float* __restrict__ h1, const float* __restrict__ hp,
    const float* __restrict__ hn,
    const float* __restrict__ W2, const float* __restrict__ b2,
    const float* __restrict__ bias2,
    const float* __restrict__ c2s, const float* __restrict__ c2p,
    const float* __restrict__ c2n,
    const float* __restrict__ k1, const float* __restrict__ bk1,
    float* __restrict__ y1) {
    int d = blockIdx.x * 256 + threadIdx.x;
    const float4* av = (const float4*)(h1 + (size_t)d * 32);
    const float4* pv = (const float4*)(hp + (size_t)d * 32);
    const float4* nv = (const float4*)(hn + (size_t)d * 32);
    float4 A[8], P[8], Nn[8];
#pragma unroll
    for (int i = 0; i < 8; i++) A[i] = av[i];
#pragma unroll
    for (int i = 0; i < 8; i++) P[i] = pv[i];
#pragma unroll
    for (int i = 0; i < 8; i++) Nn[i] = nv[i];
    float csv = c2s[0], cpv = c2p[0], cnv = c2n[0];

    float y[16];
#pragma unroll
    for (int o = 0; o < 16; o++) y[o] = bk1[o];

    // conv1 first half: y[o] += k1[o*64+f] * h1[f]
#pragma unroll
    for (int k = 0; k < 8; k++) {
        float4 a = A[k];
#pragma unroll
        for (int o = 0; o < 16; o++) {
            const float* kr = k1 + o * 64 + 4 * k;
            y[o] += kr[0] * a.x + kr[1] * a.y + kr[2] * a.z + kr[3] * a.w;
        }
    }

    // h2[f] = relu(b2+bias2 + cs*(W2a.h1) + cp*(W2b.hp) + cn*(W2c.hn)),
    // immediately folded into y via k1 second half.
    for (int f = 0; f < 32; f++) {                 // uniform loop -> s_loads
        const float* wr = W2 + f * 96;
        float s1 = 0.f, s2 = 0.f, s3 = 0.f;
#pragma unroll
        for (int k = 0; k < 8; k++) {
            float4 a = A[k], p = P[k], n = Nn[k];
            const float* w1p = wr + 4 * k;
            const float* w2p = wr + 32 + 4 * k;
            const float* w3p = wr + 64 + 4 * k;
            s1 += w1p[0] * a.x + w1p[1] * a.y + w1p[2] * a.z + w1p[3] * a.w;
            s2 += w2p[0] * p.x + w2p[1] * p.y + w2p[2] * p.z + w2p[3] * p.w;
            s3 += w3p[0] * n.x + w3p[1] * n.y + w3p[2] * n.z + w3p[3] * n.w;
        }
        float h2f = fmaxf(b2[f] + bias2[f] + csv * s1 + cpv * s2 + cnv * s3, 0.f);
        const float* kc = k1 + 32 + f;
#pragma unroll
        for (int o = 0; o < 16; o++) y[o] += kc[o * 64] * h2f;
    }

    float4* yo = (float4*)(y1 + (size_t)d * 16);
#pragma unroll
    for (int q = 0; q < 4; q++) {
        float4 v;
        v.x = y[4 * q]; v.y = y[4 * q + 1]; v.z = y[4 * q + 2]; v.w = y[4 * q + 3];
        yo[q] = v;
    }
}

// ---------------- Wfc transpose (for coalesced FC reads) ----------------

__global__ void k_transpose(const float* __restrict__ Wfc, float* __restrict__ WfcT) {
    int i = blockIdx.x * 256 + threadIdx.x;
    if (i < 128 * 416) {
        int u = i / 416, c = i - u * 416;
        WfcT[c * 128 + u] = Wfc[i];
    }
}

// ---------------- Head: maxpool -> conv2 -> FC -> classifier -> log_softmax ----

__global__ __launch_bounds__(128) void k_head(
    const float* __restrict__ y1, const float* __restrict__ k2,
    const float* __restrict__ bk2, const float* __restrict__ WfcT,
    const float* __restrict__ bfc, const float* __restrict__ Wc,
    const float* __restrict__ bc, float* __restrict__ out) {
    __shared__ float yl[1296];       // 81 positions x 16 ch, [p][ch]
    __shared__ float zl[16][41];     // after maxpool, [ch][pos<40], pad
    __shared__ float xr[416];        // conv2 out, index oc*13+t
    __shared__ float k2s[1536];
    __shared__ float fl[128];
    __shared__ float ll[10];
    int t = threadIdx.x;
    int b = blockIdx.x;
    const float* yb = y1 + (size_t)b * 1296;
    for (int i = t; i < 1296; i += 128) yl[i] = yb[i];
    for (int i = t; i < 1536; i += 128) k2s[i] = k2[i];
    __syncthreads();
    // maxpool over position pairs (drop pos 80)
    for (int i = t; i < 640; i += 128) {
        int ic = i & 15, p = i >> 4;
        zl[ic][p] = fmaxf(yl[(2 * p) * 16 + ic], yl[(2 * p + 1) * 16 + ic]);
    }
    __syncthreads();
    // conv2: 32 out-ch x 13 positions, stride 3, k=3
    for (int i = t; i < 416; i += 128) {
        int oc = i / 13, tt = i - oc * 13;
        float acc = bk2[oc];
        for (int ic = 0; ic < 16; ic++) {
            const float* kk = &k2s[(oc * 16 + ic) * 3];
            acc += zl[ic][3 * tt]     * kk[0]
                 + zl[ic][3 * tt + 1] * kk[1]
                 + zl[ic][3 * tt + 2] * kk[2];
        }
        xr[i] = acc;
    }
    __syncthreads();
    // FC 416 -> 128, one thread per output, coalesced WfcT reads
    {
        float acc = bfc[t];
        for (int i = 0; i < 416; i++) acc += xr[i] * WfcT[i * 128 + t];
        fl[t] = fmaxf(acc, 0.f);
    }
    __syncthreads();
    if (t < 10) {
        float acc = bc[t];
        for (int u = 0; u < 128; u++) acc += fl[u] * Wc[t * 128 + u];
        ll[t] = acc;
    }
    __syncthreads();
    if (t < 10) {
        float m = -1e30f;
        for (int c = 0; c < 10; c++) m = fmaxf(m, ll[c]);
        float s = 0.f;
        for (int c = 0; c < 10; c++) s += __expf(ll[c] - m);
        out[b * 10 + t] = ll[t] - m - __logf(s);
    }
}

// ---------------- launch ----------------

extern "C" void kernel_launch(void* const* d_in, const int* in_sizes, int n_in,
                              void* d_out, int out_size, void* d_ws, size_t ws_size,
                              hipStream_t stream) {
    const int*   src   = (const int*)d_in[0];
    const int*   dst   = (const int*)d_in[1];
    const float* w     = (const float*)d_in[2];
    const float* W1    = (const float*)d_in[4];
    const float* b1    = (const float*)d_in[5];
    const float* bias1 = (const float*)d_in[6];
    const float* c1s   = (const float*)d_in[7];
    const float* c1p   = (const float*)d_in[8];
    const float* c1n   = (const float*)d_in[9];
    const float* W2    = (const float*)d_in[10];
    const float* b2    = (const float*)d_in[11];
    const float* bias2 = (const float*)d_in[12];
    const float* c2s   = (const float*)d_in[13];
    const float* c2p   = (const float*)d_in[14];
    const float* c2n   = (const float*)d_in[15];
    const float* k1    = (const float*)d_in[16];
    const float* bk1   = (const float*)d_in[17];
    const float* k2    = (const float*)d_in[18];
    const float* bk2   = (const float*)d_in[19];
    const float* Wfc   = (const float*)d_in[20];
    const float* bfc   = (const float*)d_in[21];
    const float* Wc    = (const float*)d_in[22];
    const float* bc    = (const float*)d_in[23];
    const int E = in_sizes[0];
    const int NT = (E + TE - 1) / TE;

    // workspace carve (256B aligned)
    size_t off = 0;
    auto carve = [&](size_t bytes) -> char* {
        char* p = (char*)d_ws + off;
        off = (off + bytes + 255) & ~(size_t)255;
        return p;
    };
    int*   cnt    = (int*)  carve((size_t)NNODES * 4);
    int*   offs   = (int*)  carve((size_t)NNODES * 4);
    int2*  csrB   = (int2*) carve((size_t)E * 8);
    int*   H      = (int*)  carve((size_t)NT * NBUCK * 4);
    int*   T      = (int*)  carve((size_t)NBUCK * 4);
    int*   Bstart = (int*)  carve((size_t)(NBUCK + 1) * 4);
    float* spos   = (float*)carve((size_t)NNODES * 4);
    float* sneg   = (float*)carve((size_t)NNODES * 4);
    float* h1     = (float*)carve((size_t)NNODES * 32 * 4);
    float* hp     = (float*)carve((size_t)NNODES * 32 * 4);
    float* hn     = (float*)carve((size_t)NNODES * 32 * 4);
    float* y1     = (float*)carve((size_t)NNODES * 16 * 4);
    float* WfcT   = (float*)carve((size_t)128 * 416 * 4);
    (void)ws_size;

    k_hist      <<<NT, 256, 0, stream>>>(dst, H, E);
    k_colscan   <<<NBUCK / 256, 256, 0, stream>>>(H, T, NT);
    k_binscan   <<<1, 256, 0, stream>>>(T, Bstart);
    k_place     <<<NT, 256, 0, stream>>>(src, dst, w, H, Bstart, csrB, E);
    k_sortbucket<<<NBUCK, 256, 0, stream>>>(csrB, Bstart, cnt, offs);
    k_layer1    <<<NNODES / 8, 256, 0, stream>>>(cnt, offs, csrB, spos, sneg, h1,
                                                 W1, b1, bias1, c1s, c1p, c1n);
    k_transpose <<<(128 * 416 + 255) / 256, 256, 0, stream>>>(Wfc, WfcT);
    k_agg       <<<NNODES / 8, 256, 0, stream>>>(cnt, offs, csrB, spos, sneg, h1,
                                                 hp, hn);
    k_mlp       <<<NNODES / 256, 256, 0, stream>>>(h1, hp, hn, W2, b2, bias2,
                                                   c2s, c2p, c2n, k1, bk1, y1);
    k_head      <<<NGRAPH, 128, 0, stream>>>(y1, k2, bk2, WfcT, bfc, Wc, bc,
                                             (float*)d_out);
}

// Round 6
// 645.641 us; speedup vs baseline: 1.5377x; 1.0054x over previous
//
#include <hip/hip_runtime.h>
#include <hip/hip_bf16.h>

#define NNODES 331776            // 81 * 4096
#define NGRAPH 4096
#define NBUCK  2048              // buckets
#define BNODES 162               // nodes per bucket (2048*162 == 331776)
#define TE     16384             // edges per tile
#define CAP    2560              // max edges/bucket (lambda=1953, 13.7 sigma)

// ---------------- deterministic bucket sort (no global atomics) ----------------

__global__ __launch_bounds__(256) void k_hist(const int* __restrict__ dst,
                                              int* __restrict__ H, int E) {
    __shared__ int h[NBUCK];
    int t = threadIdx.x, b = blockIdx.x;
    for (int i = t; i < NBUCK; i += 256) h[i] = 0;
    __syncthreads();
    int lo = b * TE, hi = min(E, lo + TE);
    for (int e = lo + t; e < hi; e += 256)
        atomicAdd(&h[dst[e] / BNODES], 1);
    __syncthreads();
    for (int i = t; i < NBUCK; i += 256) H[b * NBUCK + i] = h[i];
}

// per-bucket exclusive scan across tiles (in place); T[bin] = total
__global__ void k_colscan(int* __restrict__ H, int* __restrict__ T, int NT) {
    int bin = blockIdx.x * 256 + threadIdx.x;
    int s = 0;
    for (int t = 0; t < NT; t++) {
        int v = H[t * NBUCK + bin];
        H[t * NBUCK + bin] = s;
        s += v;
    }
    T[bin] = s;
}

// exclusive scan over the 2048 bucket totals -> Bstart[0..NBUCK]
__global__ __launch_bounds__(256) void k_binscan(const int* __restrict__ T,
                                                 int* __restrict__ Bstart) {
    __shared__ int tmp[256];
    int t = threadIdx.x;
    int base = t * 8;
    int loc[8]; int s = 0;
#pragma unroll
    for (int i = 0; i < 8; i++) { loc[i] = s; s += T[base + i]; }
    tmp[t] = s; __syncthreads();
    for (int o = 1; o < 256; o <<= 1) {
        int a = (t >= o) ? tmp[t - o] : 0;
        __syncthreads();
        tmp[t] += a;
        __syncthreads();
    }
    int excl = tmp[t] - s;
#pragma unroll
    for (int i = 0; i < 8; i++) Bstart[base + i] = excl + loc[i];
    if (t == 255) Bstart[NBUCK] = excl + s;
}

// place edges into bucket-major order; payload packs (src | dst_local<<19, esig)
// esig = sign(w)*exp(|w|) computed once here.
__global__ __launch_bounds__(256) void k_place(
    const int* __restrict__ src, const int* __restrict__ dst,
    const float* __restrict__ w,
    const int* __restrict__ H, const int* __restrict__ Bstart,
    int2* __restrict__ csrB, int E) {
    __shared__ int cur[NBUCK];
    int t = threadIdx.x, b = blockIdx.x;
    for (int i = t; i < NBUCK; i += 256)
        cur[i] = Bstart[i] + H[b * NBUCK + i];
    __syncthreads();
    int lo = b * TE, hi = min(E, lo + TE);
    for (int e = lo + t; e < hi; e += 256) {
        int d  = dst[e];
        int sx = src[e];
        float wv = w[e];
        float es = 0.f;
        if (wv > 0.f)      es = __expf(wv);
        else if (wv < 0.f) es = -__expf(-wv);
        int bin = d / BNODES;
        int dl  = d - bin * BNODES;
        int p = atomicAdd(&cur[bin], 1);        // LDS atomic; same-bin runs -> consecutive p
        int2 pk;
        pk.x = sx | (dl << 19);
        pk.y = __float_as_int(es);
        csrB[p] = pk;
    }
}

// per-bucket counting sort (in place), emits cnt[] and offs[] for free.
__global__ __launch_bounds__(256) void k_sortbucket(
    int2* __restrict__ csrB, const int* __restrict__ Bstart,
    int* __restrict__ cnt, int* __restrict__ offs) {
    __shared__ int2 pb[CAP];
    __shared__ int lcnt[BNODES];
    __shared__ int lpos[BNODES];
    int t = threadIdx.x, b = blockIdx.x;
    int lo = Bstart[b];
    int S  = Bstart[b + 1] - lo;
    if (S > CAP) S = CAP;                        // memory-safety guard (never expected)
    for (int i = t; i < BNODES; i += 256) lcnt[i] = 0;
    __syncthreads();
    for (int i = t; i < S; i += 256) {
        int2 pk = csrB[lo + i];                  // coalesced
        pb[i] = pk;
        atomicAdd(&lcnt[pk.x >> 19], 1);
    }
    __syncthreads();
    if (t == 0) {
        int s = 0;
        for (int i = 0; i < BNODES; i++) { lpos[i] = s; s += lcnt[i]; }
    }
    __syncthreads();
    int node0 = b * BNODES;
    for (int i = t; i < BNODES; i += 256) {
        cnt[node0 + i]  = lcnt[i];
        offs[node0 + i] = lo + lpos[i];
    }
    __syncthreads();
    for (int i = t; i < S; i += 256) {
        int2 pk = pb[i];
        int dl = pk.x >> 19;
        int p = atomicAdd(&lpos[dl], 1);
        int2 outv;
        outv.x = pk.x & 0x7FFFF;                 // unpacked src
        outv.y = pk.y;                           // esig
        csrB[lo + p] = outv;                     // bucket-local, L2-hot
    }
}

// ---------------- Layer 1 (h0 = deg, 1 feature -> 32) ----------------

__global__ __launch_bounds__(256) void k_layer1(
    const int* __restrict__ cnt, const int* __restrict__ offs,
    const int2* __restrict__ csr,
    float* __restrict__ spos, float* __restrict__ sneg,
    float* __restrict__ h1,
    const float* __restrict__ W1, const float* __restrict__ b1,
    const float* __restrict__ bias1,
    const float* __restrict__ c1s, const float* __restrict__ c1p,
    const float* __restrict__ c1n) {
    int t = threadIdx.x;
    int g = t >> 5, f = t & 31;
    int d = blockIdx.x * 8 + g;
    int beg = offs[d];
    int len = cnt[d];
    float sp = 0.f, sn = 0.f, up = 0.f, un = 0.f;
    for (int j = 0; j < len; j += 32) {
        int rem = len - j;
        if (f < rem) {
            int2 sw = csr[beg + j + f];            // coalesced 8B/lane
            float es = __int_as_float(sw.y);
            float degs = (float)cnt[sw.x];          // parallel gather, L2-hot
            float ep = fmaxf(es, 0.f), en = fmaxf(-es, 0.f);
            sp += ep; sn += en; up += degs * ep; un += degs * en;
        }
    }
    for (int m = 16; m; m >>= 1) {
        sp += __shfl_xor(sp, m, 32);
        sn += __shfl_xor(sn, m, 32);
        up += __shfl_xor(up, m, 32);
        un += __shfl_xor(un, m, 32);
    }
    if (f == 0) { spos[d] = sp; sneg[d] = sn; }
    float hp = up / fmaxf(sp, 1e-20f);
    float hn = un / fmaxf(sn, 1e-20f);
    float x0 = c1s[0] * (float)len;   // deg[d] == len
    float x1 = c1p[0] * hp;
    float x2 = c1n[0] * hn;
    float v = W1[f * 3] * x0 + W1[f * 3 + 1] * x1 + W1[f * 3 + 2] * x2
            + b1[f] + bias1[f];
    h1[d * 32 + f] = fmaxf(v, 0.f);                 // coalesced 128B/node
}

// ---------------- Layer-2 aggregation only (no LDS -> max occupancy) ----------
// Half-wave per node; writes normalized hp/hn planes coalesced.

__global__ __launch_bounds__(256) void k_agg(
    const int* __restrict__ cnt, const int* __restrict__ offs,
    const int2* __restrict__ csr,
    const float* __restrict__ spos, const float* __restrict__ sneg,
    const float* __restrict__ h1,
    float* __restrict__ hp, float* __restrict__ hn) {
    int t = threadIdx.x;
    int g = t >> 5, f = t & 31;
    int d = blockIdx.x * 8 + g;     // NNODES % 8 == 0
    int beg = offs[d];
    int len = cnt[d];
    float ap = 0.f, an = 0.f;
    for (int j = 0; j < len; j += 32) {
        int rem = len - j;
        int sx = 0;
        float es = 0.f;
        if (f < rem) {
            int2 sw = csr[beg + j + f];            // coalesced 8B/lane
            sx = sw.x;
            es = __int_as_float(sw.y);
        }
        int n = rem < 32 ? rem : 32;
        int q = 0;
        for (; q + 4 <= n; q += 4) {
            int   s0 = __shfl(sx, q,     32);
            int   s1 = __shfl(sx, q + 1, 32);
            int   s2 = __shfl(sx, q + 2, 32);
            int   s3 = __shfl(sx, q + 3, 32);
            float e0 = __shfl(es, q,     32);
            float e1 = __shfl(es, q + 1, 32);
            float e2 = __shfl(es, q + 2, 32);
            float e3 = __shfl(es, q + 3, 32);
            float h0  = h1[s0 * 32 + f];            // 4 independent gathers in flight
            float hv1 = h1[s1 * 32 + f];
            float hv2 = h1[s2 * 32 + f];
            float hv3 = h1[s3 * 32 + f];
            ap += fmaxf(e0, 0.f) * h0;  an += fmaxf(-e0, 0.f) * h0;
            ap += fmaxf(e1, 0.f) * hv1; an += fmaxf(-e1, 0.f) * hv1;
            ap += fmaxf(e2, 0.f) * hv2; an += fmaxf(-e2, 0.f) * hv2;
            ap += fmaxf(e3, 0.f) * hv3; an += fmaxf(-e3, 0.f) * hv3;
        }
        for (; q < n; q++) {
            int   s0 = __shfl(sx, q, 32);
            float e0 = __shfl(es, q, 32);
            float h0 = h1[s0 * 32 + f];
            ap += fmaxf(e0, 0.f) * h0;
            an += fmaxf(-e0, 0.f) * h0;
        }
    }
    hp[d * 32 + f] = ap / fmaxf(spos[d], 1e-20f);
    hn[d * 32 + f] = an / fmaxf(sneg[d], 1e-20f);
}

// ---------------- Layer-2 MLP + fused conv1, one THREAD per node -------------
// h1/hp/hn rows in registers; W2/k1 via uniform (scalar) loads -> SGPR/K$.
// launch_bounds(256,2): VGPR cap ~256 so the 96-reg node data STAYS resident
// (at the default cap of 80 the compiler re-loads it inside the f-loop -> 125us).

__global__ __launch_bounds__(256, 2) void k_mlp(
    const float* __restrict__ h1, const float* __restrict__ hp,
    const float* __restrict__ hn,
    const float* __restrict__ W2, const float* __restrict__ b2,
    const float* __restrict__ bias2,
    const float* __restrict__ c2s, const float* __restrict__ c2p,
    const float* __restrict__ c2n,
    const float* __restrict__ k1, const float* __restrict__ bk1,
    float* __restrict__ y1) {
    int d = blockIdx.x * 256 + threadIdx.x;
    const float4* av = (const float4*)(h1 + (size_t)d * 32);
    const float4* pv = (const float4*)(hp + (size_t)d * 32);
    const float4* nv = (const float4*)(hn + (size_t)d * 32);
    float4 A[8], P[8], Nn[8];
#pragma unroll
    for (int i = 0; i < 8; i++) A[i] = av[i];
#pragma unroll
    for (int i = 0; i < 8; i++) P[i] = pv[i];
#pragma unroll
    for (int i = 0; i < 8; i++) Nn[i] = nv[i];
    float csv = c2s[0], cpv = c2p[0], cnv = c2n[0];

    float y[16];
#pragma unroll
    for (int o = 0; o < 16; o++) y[o] = bk1[o];

    // conv1 first half: y[o] += k1[o*64+f] * h1[f]
#pragma unroll
    for (int k = 0; k < 8; k++) {
        float4 a = A[k];
#pragma unroll
        for (int o = 0; o < 16; o++) {
            const float* kr = k1 + o * 64 + 4 * k;
            y[o] += kr[0] * a.x + kr[1] * a.y + kr[2] * a.z + kr[3] * a.w;
        }
    }

    // h2[f] = relu(b2+bias2 + cs*(W2a.h1) + cp*(W2b.hp) + cn*(W2c.hn)),
    // immediately folded into y via k1 second half.
    for (int f = 0; f < 32; f++) {                 // uniform loop -> s_loads
        const float* wr = W2 + f * 96;
        float s1 = 0.f, s2 = 0.f, s3 = 0.f;
#pragma unroll
        for (int k = 0; k < 8; k++) {
            float4 a = A[k], p = P[k], n = Nn[k];
            const float* w1p = wr + 4 * k;
            const float* w2p = wr + 32 + 4 * k;
            const float* w3p = wr + 64 + 4 * k;
            s1 += w1p[0] * a.x + w1p[1] * a.y + w1p[2] * a.z + w1p[3] * a.w;
            s2 += w2p[0] * p.x + w2p[1] * p.y + w2p[2] * p.z + w2p[3] * p.w;
            s3 += w3p[0] * n.x + w3p[1] * n.y + w3p[2] * n.z + w3p[3] * n.w;
        }
        float h2f = fmaxf(b2[f] + bias2[f] + csv * s1 + cpv * s2 + cnv * s3, 0.f);
        const float* kc = k1 + 32 + f;
#pragma unroll
        for (int o = 0; o < 16; o++) y[o] += kc[o * 64] * h2f;
    }

    float4* yo = (float4*)(y1 + (size_t)d * 16);
#pragma unroll
    for (int q = 0; q < 4; q++) {
        float4 v;
        v.x = y[4 * q]; v.y = y[4 * q + 1]; v.z = y[4 * q + 2]; v.w = y[4 * q + 3];
        yo[q] = v;
    }
}

// ---------------- Wfc transpose (for coalesced FC reads) ----------------

__global__ void k_transpose(const float* __restrict__ Wfc, float* __restrict__ WfcT) {
    int i = blockIdx.x * 256 + threadIdx.x;
    if (i < 128 * 416) {
        int u = i / 416, c = i - u * 416;
        WfcT[c * 128 + u] = Wfc[i];
    }
}

// ---------------- Head: maxpool -> conv2 -> FC -> classifier -> log_softmax ----

__global__ __launch_bounds__(128) void k_head(
    const float* __restrict__ y1, const float* __restrict__ k2,
    const float* __restrict__ bk2, const float* __restrict__ WfcT,
    const float* __restrict__ bfc, const float* __restrict__ Wc,
    const float* __restrict__ bc, float* __restrict__ out) {
    __shared__ float yl[1296];       // 81 positions x 16 ch, [p][ch]
    __shared__ float zl[16][41];     // after maxpool, [ch][pos<40], pad
    __shared__ float xr[416];        // conv2 out, index oc*13+t
    __shared__ float k2s[1536];
    __shared__ float fl[128];
    __shared__ float ll[10];
    int t = threadIdx.x;
    int b = blockIdx.x;
    const float* yb = y1 + (size_t)b * 1296;
    for (int i = t; i < 1296; i += 128) yl[i] = yb[i];
    for (int i = t; i < 1536; i += 128) k2s[i] = k2[i];
    __syncthreads();
    // maxpool over position pairs (drop pos 80)
    for (int i = t; i < 640; i += 128) {
        int ic = i & 15, p = i >> 4;
        zl[ic][p] = fmaxf(yl[(2 * p) * 16 + ic], yl[(2 * p + 1) * 16 + ic]);
    }
    __syncthreads();
    // conv2: 32 out-ch x 13 positions, stride 3, k=3
    for (int i = t; i < 416; i += 128) {
        int oc = i / 13, tt = i - oc * 13;
        float acc = bk2[oc];
        for (int ic = 0; ic < 16; ic++) {
            const float* kk = &k2s[(oc * 16 + ic) * 3];
            acc += zl[ic][3 * tt]     * kk[0]
                 + zl[ic][3 * tt + 1] * kk[1]
                 + zl[ic][3 * tt + 2] * kk[2];
        }
        xr[i] = acc;
    }
    __syncthreads();
    // FC 416 -> 128, one thread per output, coalesced WfcT reads
    {
        float acc = bfc[t];
        for (int i = 0; i < 416; i++) acc += xr[i] * WfcT[i * 128 + t];
        fl[t] = fmaxf(acc, 0.f);
    }
    __syncthreads();
    if (t < 10) {
        float acc = bc[t];
        for (int u = 0; u < 128; u++) acc += fl[u] * Wc[t * 128 + u];
        ll[t] = acc;
    }
    __syncthreads();
    if (t < 10) {
        float m = -1e30f;
        for (int c = 0; c < 10; c++) m = fmaxf(m, ll[c]);
        float s = 0.f;
        for (int c = 0; c < 10; c++) s += __expf(ll[c] - m);
        out[b * 10 + t] = ll[t] - m - __logf(s);
    }
}

// ---------------- launch ----------------

extern "C" void kernel_launch(void* const* d_in, const int* in_sizes, int n_in,
                              void* d_out, int out_size, void* d_ws, size_t ws_size,
                              hipStream_t stream) {
    const int*   src   = (const int*)d_in[0];
    const int*   dst   = (const int*)d_in[1];
    const float* w     = (const float*)d_in[2];
    const float* W1    = (const float*)d_in[4];
    const float* b1    = (const float*)d_in[5];
    const float* bias1 = (const float*)d_in[6];
    const float* c1s   = (const float*)d_in[7];
    const float* c1p   = (const float*)d_in[8];
    const float* c1n   = (const float*)d_in[9];
    const float* W2    = (const float*)d_in[10];
    const float* b2    = (const float*)d_in[11];
    const float* bias2 = (const float*)d_in[12];
    const float* c2s   = (const float*)d_in[13];
    const float* c2p   = (const float*)d_in[14];
    const float* c2n   = (const float*)d_in[15];
    const float* k1    = (const float*)d_in[16];
    const float* bk1   = (const float*)d_in[17];
    const float* k2    = (const float*)d_in[18];
    const float* bk2   = (const float*)d_in[19];
    const float* Wfc   = (const float*)d_in[20];
    const float* bfc   = (const float*)d_in[21];
    const float* Wc    = (const float*)d_in[22];
    const float* bc    = (const float*)d_in[23];
    const int E = in_sizes[0];
    const int NT = (E + TE - 1) / TE;

    // workspace carve (256B aligned)
    size_t off = 0;
    auto carve = [&](size_t bytes) -> char* {
        char* p = (char*)d_ws + off;
        off = (off + bytes + 255) & ~(size_t)255;
        return p;
    };
    int*   cnt    = (int*)  carve((size_t)NNODES * 4);
    int*   offs   = (int*)  carve((size_t)NNODES * 4);
    int2*  csrB   = (int2*) carve((size_t)E * 8);
    int*   H      = (int*)  carve((size_t)NT * NBUCK * 4);
    int*   T      = (int*)  carve((size_t)NBUCK * 4);
    int*   Bstart = (int*)  carve((size_t)(NBUCK + 1) * 4);
    float* spos   = (float*)carve((size_t)NNODES * 4);
    float* sneg   = (float*)carve((size_t)NNODES * 4);
    float* h1     = (float*)carve((size_t)NNODES * 32 * 4);
    float* hp     = (float*)carve((size_t)NNODES * 32 * 4);
    float* hn     = (float*)carve((size_t)NNODES * 32 * 4);
    float* y1     = (float*)carve((size_t)NNODES * 16 * 4);
    float* WfcT   = (float*)carve((size_t)128 * 416 * 4);
    (void)ws_size;

    k_hist      <<<NT, 256, 0, stream>>>(dst, H, E);
    k_colscan   <<<NBUCK / 256, 256, 0, stream>>>(H, T, NT);
    k_binscan   <<<1, 256, 0, stream>>>(T, Bstart);
    k_place     <<<NT, 256, 0, stream>>>(src, dst, w, H, Bstart, csrB, E);
    k_sortbucket<<<NBUCK, 256, 0, stream>>>(csrB, Bstart, cnt, offs);
    k_layer1    <<<NNODES / 8, 256, 0, stream>>>(cnt, offs, csrB, spos, sneg, h1,
                                                 W1, b1, bias1, c1s, c1p, c1n);
    k_transpose <<<(128 * 416 + 255) / 256, 256, 0, stream>>>(Wfc, WfcT);
    k_agg       <<<NNODES / 8, 256, 0, stream>>>(cnt, offs, csrB, spos, sneg, h1,
                                                 hp, hn);
    k_mlp       <<<NNODES / 256, 256, 0, stream>>>(h1, hp, hn, W2, b2, bias2,
                                                   c2s, c2p, c2n, k1, bk1, y1);
    k_head      <<<NGRAPH, 128, 0, stream>>>(y1, k2, bk2, WfcT, bfc, Wc, bc,
                                             (float*)d_out);
}

// Round 7
// 634.229 us; speedup vs baseline: 1.5654x; 1.0180x over previous
//
#include <hip/hip_runtime.h>
#include <hip/hip_bf16.h>

#define NNODES 331776            // 81 * 4096
#define NGRAPH 4096
#define NBUCK  2048              // buckets
#define BNODES 162               // nodes per bucket (2048*162 == 331776)
#define TE     16384             // edges per tile
#define CAP    2560              // max edges/bucket (lambda=1953, 13.7 sigma)

// ---------------- deterministic bucket sort (no global atomics) ----------------

__global__ __launch_bounds__(256) void k_hist(const int* __restrict__ dst,
                                              int* __restrict__ H, int E) {
    __shared__ int h[NBUCK];
    int t = threadIdx.x, b = blockIdx.x;
    for (int i = t; i < NBUCK; i += 256) h[i] = 0;
    __syncthreads();
    int lo = b * TE, hi = min(E, lo + TE);
    for (int e = lo + t; e < hi; e += 256)
        atomicAdd(&h[dst[e] / BNODES], 1);
    __syncthreads();
    for (int i = t; i < NBUCK; i += 256) H[b * NBUCK + i] = h[i];
}

// per-bucket exclusive scan across tiles (in place); T[bin] = total
__global__ void k_colscan(int* __restrict__ H, int* __restrict__ T, int NT) {
    int bin = blockIdx.x * 256 + threadIdx.x;
    int s = 0;
    for (int t = 0; t < NT; t++) {
        int v = H[t * NBUCK + bin];
        H[t * NBUCK + bin] = s;
        s += v;
    }
    T[bin] = s;
}

// exclusive scan over the 2048 bucket totals -> Bstart[0..NBUCK]
__global__ __launch_bounds__(256) void k_binscan(const int* __restrict__ T,
                                                 int* __restrict__ Bstart) {
    __shared__ int tmp[256];
    int t = threadIdx.x;
    int base = t * 8;
    int loc[8]; int s = 0;
#pragma unroll
    for (int i = 0; i < 8; i++) { loc[i] = s; s += T[base + i]; }
    tmp[t] = s; __syncthreads();
    for (int o = 1; o < 256; o <<= 1) {
        int a = (t >= o) ? tmp[t - o] : 0;
        __syncthreads();
        tmp[t] += a;
        __syncthreads();
    }
    int excl = tmp[t] - s;
#pragma unroll
    for (int i = 0; i < 8; i++) Bstart[base + i] = excl + loc[i];
    if (t == 255) Bstart[NBUCK] = excl + s;
}

// place edges into bucket-major order; payload packs (src | dst_local<<19, esig)
// esig = sign(w)*exp(|w|) computed once here.
__global__ __launch_bounds__(256) void k_place(
    const int* __restrict__ src, const int* __restrict__ dst,
    const float* __restrict__ w,
    const int* __restrict__ H, const int* __restrict__ Bstart,
    int2* __restrict__ csrB, int E) {
    __shared__ int cur[NBUCK];
    int t = threadIdx.x, b = blockIdx.x;
    for (int i = t; i < NBUCK; i += 256)
        cur[i] = Bstart[i] + H[b * NBUCK + i];
    __syncthreads();
    int lo = b * TE, hi = min(E, lo + TE);
    for (int e = lo + t; e < hi; e += 256) {
        int d  = dst[e];
        int sx = src[e];
        float wv = w[e];
        float es = 0.f;
        if (wv > 0.f)      es = __expf(wv);
        else if (wv < 0.f) es = -__expf(-wv);
        int bin = d / BNODES;
        int dl  = d - bin * BNODES;
        int p = atomicAdd(&cur[bin], 1);        // LDS atomic; same-bin runs -> consecutive p
        int2 pk;
        pk.x = sx | (dl << 19);
        pk.y = __float_as_int(es);
        csrB[p] = pk;
    }
}

// per-bucket counting sort (in place), emits cnt[] and offs[] for free.
__global__ __launch_bounds__(256) void k_sortbucket(
    int2* __restrict__ csrB, const int* __restrict__ Bstart,
    int* __restrict__ cnt, int* __restrict__ offs) {
    __shared__ int2 pb[CAP];
    __shared__ int lcnt[BNODES];
    __shared__ int lpos[BNODES];
    int t = threadIdx.x, b = blockIdx.x;
    int lo = Bstart[b];
    int S  = Bstart[b + 1] - lo;
    if (S > CAP) S = CAP;                        // memory-safety guard (never expected)
    for (int i = t; i < BNODES; i += 256) lcnt[i] = 0;
    __syncthreads();
    for (int i = t; i < S; i += 256) {
        int2 pk = csrB[lo + i];                  // coalesced
        pb[i] = pk;
        atomicAdd(&lcnt[pk.x >> 19], 1);
    }
    __syncthreads();
    if (t == 0) {
        int s = 0;
        for (int i = 0; i < BNODES; i++) { lpos[i] = s; s += lcnt[i]; }
    }
    __syncthreads();
    int node0 = b * BNODES;
    for (int i = t; i < BNODES; i += 256) {
        cnt[node0 + i]  = lcnt[i];
        offs[node0 + i] = lo + lpos[i];
    }
    __syncthreads();
    for (int i = t; i < S; i += 256) {
        int2 pk = pb[i];
        int dl = pk.x >> 19;
        int p = atomicAdd(&lpos[dl], 1);
        int2 outv;
        outv.x = pk.x & 0x7FFFF;                 // unpacked src
        outv.y = pk.y;                           // esig
        csrB[lo + p] = outv;                     // bucket-local, L2-hot
    }
}

// ---------------- Layer 1 (h0 = deg, 1 feature -> 32) ----------------

__global__ __launch_bounds__(256) void k_layer1(
    const int* __restrict__ cnt, const int* __restrict__ offs,
    const int2* __restrict__ csr,
    float* __restrict__ spos, float* __restrict__ sneg,
    float* __restrict__ h1,
    const float* __restrict__ W1, const float* __restrict__ b1,
    const float* __restrict__ bias1,
    const float* __restrict__ c1s, const float* __restrict__ c1p,
    const float* __restrict__ c1n) {
    int t = threadIdx.x;
    int g = t >> 5, f = t & 31;
    int d = blockIdx.x * 8 + g;
    int beg = offs[d];
    int len = cnt[d];
    float sp = 0.f, sn = 0.f, up = 0.f, un = 0.f;
    for (int j = 0; j < len; j += 32) {
        int rem = len - j;
        if (f < rem) {
            int2 sw = csr[beg + j + f];            // coalesced 8B/lane
            float es = __int_as_float(sw.y);
            float degs = (float)cnt[sw.x];          // parallel gather, L2-hot
            float ep = fmaxf(es, 0.f), en = fmaxf(-es, 0.f);
            sp += ep; sn += en; up += degs * ep; un += degs * en;
        }
    }
    for (int m = 16; m; m >>= 1) {
        sp += __shfl_xor(sp, m, 32);
        sn += __shfl_xor(sn, m, 32);
        up += __shfl_xor(up, m, 32);
        un += __shfl_xor(un, m, 32);
    }
    if (f == 0) { spos[d] = sp; sneg[d] = sn; }
    float hp = up / fmaxf(sp, 1e-20f);
    float hn = un / fmaxf(sn, 1e-20f);
    float x0 = c1s[0] * (float)len;   // deg[d] == len
    float x1 = c1p[0] * hp;
    float x2 = c1n[0] * hn;
    float v = W1[f * 3] * x0 + W1[f * 3 + 1] * x1 + W1[f * 3 + 2] * x2
            + b1[f] + bias1[f];
    h1[d * 32 + f] = fmaxf(v, 0.f);                 // coalesced 128B/node
}

// ---------------- Layer-2 aggregation only (no LDS -> max occupancy) ----------
// Half-wave per node; writes normalized hp/hn planes coalesced.

__global__ __launch_bounds__(256) void k_agg(
    const int* __restrict__ cnt, const int* __restrict__ offs,
    const int2* __restrict__ csr,
    const float* __restrict__ spos, const float* __restrict__ sneg,
    const float* __restrict__ h1,
    float* __restrict__ hp, float* __restrict__ hn) {
    int t = threadIdx.x;
    int g = t >> 5, f = t & 31;
    int d = blockIdx.x * 8 + g;     // NNODES % 8 == 0
    int beg = offs[d];
    int len = cnt[d];
    float ap = 0.f, an = 0.f;
    for (int j = 0; j < len; j += 32) {
        int rem = len - j;
        int sx = 0;
        float es = 0.f;
        if (f < rem) {
            int2 sw = csr[beg + j + f];            // coalesced 8B/lane
            sx = sw.x;
            es = __int_as_float(sw.y);
        }
        int n = rem < 32 ? rem : 32;
        int q = 0;
        for (; q + 4 <= n; q += 4) {
            int   s0 = __shfl(sx, q,     32);
            int   s1 = __shfl(sx, q + 1, 32);
            int   s2 = __shfl(sx, q + 2, 32);
            int   s3 = __shfl(sx, q + 3, 32);
            float e0 = __shfl(es, q,     32);
            float e1 = __shfl(es, q + 1, 32);
            float e2 = __shfl(es, q + 2, 32);
            float e3 = __shfl(es, q + 3, 32);
            float h0  = h1[s0 * 32 + f];            // 4 independent gathers in flight
            float hv1 = h1[s1 * 32 + f];
            float hv2 = h1[s2 * 32 + f];
            float hv3 = h1[s3 * 32 + f];
            ap += fmaxf(e0, 0.f) * h0;  an += fmaxf(-e0, 0.f) * h0;
            ap += fmaxf(e1, 0.f) * hv1; an += fmaxf(-e1, 0.f) * hv1;
            ap += fmaxf(e2, 0.f) * hv2; an += fmaxf(-e2, 0.f) * hv2;
            ap += fmaxf(e3, 0.f) * hv3; an += fmaxf(-e3, 0.f) * hv3;
        }
        for (; q < n; q++) {
            int   s0 = __shfl(sx, q, 32);
            float e0 = __shfl(es, q, 32);
            float h0 = h1[s0 * 32 + f];
            ap += fmaxf(e0, 0.f) * h0;
            an += fmaxf(-e0, 0.f) * h0;
        }
    }
    hp[d * 32 + f] = ap / fmaxf(spos[d], 1e-20f);
    hn[d * 32 + f] = an / fmaxf(sneg[d], 1e-20f);
}

// ---------------- Layer-2 MLP + fused conv1, one THREAD per node -------------
// THREE sequential passes (h1, hp, hn) so peak live set is ~70 floats:
// acc[32] + one 32-float row. No inner-loop data reloads possible to "spill to".
// W2/k1 via uniform (scalar) loads -> SGPR/K$.

__global__ __launch_bounds__(256, 2) void k_mlp(
    const float* __restrict__ h1, const float* __restrict__ hp,
    const float* __restrict__ hn,
    const float* __restrict__ W2, const float* __restrict__ b2,
    const float* __restrict__ bias2,
    const float* __restrict__ c2s, const float* __restrict__ c2p,
    const float* __restrict__ c2n,
    const float* __restrict__ k1, const float* __restrict__ bk1,
    float* __restrict__ y1) {
    int d = blockIdx.x * 256 + threadIdx.x;
    float acc[32];
#pragma unroll
    for (int f = 0; f < 32; f++) acc[f] = b2[f] + bias2[f];

#pragma unroll 1
    for (int p = 0; p < 3; p++) {                  // sequential: bounds liveness
        const float* base = (p == 0) ? h1 : ((p == 1) ? hp : hn);
        float sc = (p == 0) ? c2s[0] : ((p == 1) ? c2p[0] : c2n[0]);
        const float4* xv = (const float4*)(base + (size_t)d * 32);
        float4 X[8];
#pragma unroll
        for (int i = 0; i < 8; i++) X[i] = xv[i];
        const float* wb = W2 + p * 32;             // third of each W2 row
#pragma unroll
        for (int f = 0; f < 32; f++) {
            const float* wr = wb + f * 96;         // uniform -> s_load
            float s = 0.f;
#pragma unroll
            for (int k = 0; k < 8; k++) {
                float4 x = X[k];
                s += wr[4 * k]     * x.x + wr[4 * k + 1] * x.y
                   + wr[4 * k + 2] * x.z + wr[4 * k + 3] * x.w;
            }
            acc[f] += sc * s;
        }
    }
#pragma unroll
    for (int f = 0; f < 32; f++) acc[f] = fmaxf(acc[f], 0.f);   // h2

    float y[16];
    // conv1 second half: y[o] = bk1[o] + sum_f k1[o*64+32+f] * h2[f]
#pragma unroll
    for (int o = 0; o < 16; o++) {
        const float* kr = k1 + o * 64 + 32;
        float s = bk1[o];
#pragma unroll
        for (int f = 0; f < 32; f++) s += kr[f] * acc[f];
        y[o] = s;
    }
    // conv1 first half: reload h1 row (L1-hot) after acc is dead
    {
        const float4* av = (const float4*)(h1 + (size_t)d * 32);
        float4 A[8];
#pragma unroll
        for (int i = 0; i < 8; i++) A[i] = av[i];
#pragma unroll
        for (int o = 0; o < 16; o++) {
            const float* kr = k1 + o * 64;
            float s = 0.f;
#pragma unroll
            for (int k = 0; k < 8; k++) {
                float4 a = A[k];
                s += kr[4 * k]     * a.x + kr[4 * k + 1] * a.y
                   + kr[4 * k + 2] * a.z + kr[4 * k + 3] * a.w;
            }
            y[o] += s;
        }
    }
    float4* yo = (float4*)(y1 + (size_t)d * 16);
#pragma unroll
    for (int q = 0; q < 4; q++) {
        float4 v;
        v.x = y[4 * q]; v.y = y[4 * q + 1]; v.z = y[4 * q + 2]; v.w = y[4 * q + 3];
        yo[q] = v;
    }
}

// ---------------- Wfc transpose (for coalesced FC reads) ----------------

__global__ void k_transpose(const float* __restrict__ Wfc, float* __restrict__ WfcT) {
    int i = blockIdx.x * 256 + threadIdx.x;
    if (i < 128 * 416) {
        int u = i / 416, c = i - u * 416;
        WfcT[c * 128 + u] = Wfc[i];
    }
}

// ---------------- Head: maxpool -> conv2 -> FC -> classifier -> log_softmax ----

__global__ __launch_bounds__(128) void k_head(
    const float* __restrict__ y1, const float* __restrict__ k2,
    const float* __restrict__ bk2, const float* __restrict__ WfcT,
    const float* __restrict__ bfc, const float* __restrict__ Wc,
    const float* __restrict__ bc, float* __restrict__ out) {
    __shared__ float yl[1296];       // 81 positions x 16 ch, [p][ch]
    __shared__ float zl[16][41];     // after maxpool, [ch][pos<40], pad
    __shared__ float xr[416];        // conv2 out, index oc*13+t
    __shared__ float k2s[1536];
    __shared__ float fl[128];
    __shared__ float ll[10];
    int t = threadIdx.x;
    int b = blockIdx.x;
    const float* yb = y1 + (size_t)b * 1296;
    for (int i = t; i < 1296; i += 128) yl[i] = yb[i];
    for (int i = t; i < 1536; i += 128) k2s[i] = k2[i];
    __syncthreads();
    // maxpool over position pairs (drop pos 80)
    for (int i = t; i < 640; i += 128) {
        int ic = i & 15, p = i >> 4;
        zl[ic][p] = fmaxf(yl[(2 * p) * 16 + ic], yl[(2 * p + 1) * 16 + ic]);
    }
    __syncthreads();
    // conv2: 32 out-ch x 13 positions, stride 3, k=3
    for (int i = t; i < 416; i += 128) {
        int oc = i / 13, tt = i - oc * 13;
        float acc = bk2[oc];
        for (int ic = 0; ic < 16; ic++) {
            const float* kk = &k2s[(oc * 16 + ic) * 3];
            acc += zl[ic][3 * tt]     * kk[0]
                 + zl[ic][3 * tt + 1] * kk[1]
                 + zl[ic][3 * tt + 2] * kk[2];
        }
        xr[i] = acc;
    }
    __syncthreads();
    // FC 416 -> 128, one thread per output, coalesced WfcT reads
    {
        float acc = bfc[t];
        for (int i = 0; i < 416; i++) acc += xr[i] * WfcT[i * 128 + t];
        fl[t] = fmaxf(acc, 0.f);
    }
    __syncthreads();
    if (t < 10) {
        float acc = bc[t];
        for (int u = 0; u < 128; u++) acc += fl[u] * Wc[t * 128 + u];
        ll[t] = acc;
    }
    __syncthreads();
    if (t < 10) {
        float m = -1e30f;
        for (int c = 0; c < 10; c++) m = fmaxf(m, ll[c]);
        float s = 0.f;
        for (int c = 0; c < 10; c++) s += __expf(ll[c] - m);
        out[b * 10 + t] = ll[t] - m - __logf(s);
    }
}

// ---------------- launch ----------------

extern "C" void kernel_launch(void* const* d_in, const int* in_sizes, int n_in,
                              void* d_out, int out_size, void* d_ws, size_t ws_size,
                              hipStream_t stream) {
    const int*   src   = (const int*)d_in[0];
    const int*   dst   = (const int*)d_in[1];
    const float* w     = (const float*)d_in[2];
    const float* W1    = (const float*)d_in[4];
    const float* b1    = (const float*)d_in[5];
    const float* bias1 = (const float*)d_in[6];
    const float* c1s   = (const float*)d_in[7];
    const float* c1p   = (const float*)d_in[8];
    const float* c1n   = (const float*)d_in[9];
    const float* W2    = (const float*)d_in[10];
    const float* b2    = (const float*)d_in[11];
    const float* bias2 = (const float*)d_in[12];
    const float* c2s   = (const float*)d_in[13];
    const float* c2p   = (const float*)d_in[14];
    const float* c2n   = (const float*)d_in[15];
    const float* k1    = (const float*)d_in[16];
    const float* bk1   = (const float*)d_in[17];
    const float* k2    = (const float*)d_in[18];
    const float* bk2   = (const float*)d_in[19];
    const float* Wfc   = (const float*)d_in[20];
    const float* bfc   = (const float*)d_in[21];
    const float* Wc    = (const float*)d_in[22];
    const float* bc    = (const float*)d_in[23];
    const int E = in_sizes[0];
    const int NT = (E + TE - 1) / TE;

    // workspace carve (256B aligned)
    size_t off = 0;
    auto carve = [&](size_t bytes) -> char* {
        char* p = (char*)d_ws + off;
        off = (off + bytes + 255) & ~(size_t)255;
        return p;
    };
    int*   cnt    = (int*)  carve((size_t)NNODES * 4);
    int*   offs   = (int*)  carve((size_t)NNODES * 4);
    int2*  csrB   = (int2*) carve((size_t)E * 8);
    int*   H      = (int*)  carve((size_t)NT * NBUCK * 4);
    int*   T      = (int*)  carve((size_t)NBUCK * 4);
    int*   Bstart = (int*)  carve((size_t)(NBUCK + 1) * 4);
    float* spos   = (float*)carve((size_t)NNODES * 4);
    float* sneg   = (float*)carve((size_t)NNODES * 4);
    float* h1     = (float*)carve((size_t)NNODES * 32 * 4);
    float* hp     = (float*)carve((size_t)NNODES * 32 * 4);
    float* hn     = (float*)carve((size_t)NNODES * 32 * 4);
    float* y1     = (float*)carve((size_t)NNODES * 16 * 4);
    float* WfcT   = (float*)carve((size_t)128 * 416 * 4);
    (void)ws_size;

    k_hist      <<<NT, 256, 0, stream>>>(dst, H, E);
    k_colscan   <<<NBUCK / 256, 256, 0, stream>>>(H, T, NT);
    k_binscan   <<<1, 256, 0, stream>>>(T, Bstart);
    k_place     <<<NT, 256, 0, stream>>>(src, dst, w, H, Bstart, csrB, E);
    k_sortbucket<<<NBUCK, 256, 0, stream>>>(csrB, Bstart, cnt, offs);
    k_layer1    <<<NNODES / 8, 256, 0, stream>>>(cnt, offs, csrB, spos, sneg, h1,
                                                 W1, b1, bias1, c1s, c1p, c1n);
    k_transpose <<<(128 * 416 + 255) / 256, 256, 0, stream>>>(Wfc, WfcT);
    k_agg       <<<NNODES / 8, 256, 0, stream>>>(cnt, offs, csrB, spos, sneg, h1,
                                                 hp, hn);
    k_mlp       <<<NNODES / 256, 256, 0, stream>>>(h1, hp, hn, W2, b2, bias2,
                                                   c2s, c2p, c2n, k1, bk1, y1);
    k_head      <<<NGRAPH, 128, 0, stream>>>(y1, k2, bk2, WfcT, bfc, Wc, bc,
                                             (float*)d_out);
}